// Round 1
// baseline (280.826 us; speedup 1.0000x reference)
//
#include <hip/hip_runtime.h>

// Layouts: all intermediates are FEATURE-MAJOR: h[b][f][n], n in [0,4096) = 64x64 grid.
// GNN layer rewritten exactly as: h' = relu( agg(h) @ W + rowsum*b ),
// agg(h)[n] = sum_{nb of n} h[nb] / (deg(n)+1e-6), rowsum(n) = deg/(deg+1e-6).

__global__ void zero_kernel(float* __restrict__ p) {
    p[blockIdx.x * 256 + threadIdx.x] = 0.f;
}

// ---------------- embed: h0[b][d][n] = relu(relu(x@e1+b1)@e2+b2), thread-per-node ----------------
__global__ __launch_bounds__(256) void embed_kernel(
    const float* __restrict__ obs, const float* __restrict__ e1w,
    const float* __restrict__ e1b, const float* __restrict__ e2w,
    const float* __restrict__ e2b, float* __restrict__ h0)
{
    __shared__ float s1[16 * 64];
    __shared__ float s2[64 * 64];
    __shared__ float sb1[64];
    __shared__ float sb2[64];
    const int tid = threadIdx.x;
    for (int e = tid; e < 16 * 64; e += 256) s1[e] = e1w[e];
    for (int e = tid; e < 64 * 64; e += 256) s2[e] = e2w[e];
    if (tid < 64) { sb1[tid] = e1b[tid]; sb2[tid] = e2b[tid]; }
    __syncthreads();

    const int gid = blockIdx.x * 256 + tid;   // 0..65535
    const int b = gid >> 12;
    const int n = gid & 4095;
    const float* ob = obs + ((size_t)b << 16) + n;   // obs[b][c][n], c-stride 4096

    float x[16];
#pragma unroll
    for (int c = 0; c < 16; c++) x[c] = ob[(size_t)c << 12];

    float h[64];
#pragma unroll
    for (int d = 0; d < 64; d++) h[d] = sb1[d];
#pragma unroll
    for (int c = 0; c < 16; c++) {
        const float xv = x[c];
#pragma unroll
        for (int d = 0; d < 64; d++) h[d] = fmaf(xv, s1[c * 64 + d], h[d]);
    }
#pragma unroll
    for (int d = 0; d < 64; d++) h[d] = fmaxf(h[d], 0.f);

    float o[64];
#pragma unroll
    for (int d = 0; d < 64; d++) o[d] = sb2[d];
#pragma unroll
    for (int k = 0; k < 64; k++) {
        const float hv = h[k];
#pragma unroll
        for (int d = 0; d < 64; d++) o[d] = fmaf(hv, s2[k * 64 + d], o[d]);
    }
    float* hp = h0 + ((size_t)b << 18) + n;   // h0[b][d][n]
#pragma unroll
    for (int d = 0; d < 64; d++) hp[(size_t)d << 12] = fmaxf(o[d], 0.f);
}

// ---------------- GNN layer: block = (batch b, image row), tile 64 nodes x 128 douts ----------------
// A-operand aggregated on load (4-neighbor avg). MEAN=true fuses the node-mean (no hout).
template <int K, bool MEAN>
__global__ __launch_bounds__(256) void gnn_kernel(
    const float* __restrict__ hin, const float* __restrict__ W,
    const float* __restrict__ bias, float* __restrict__ hout,
    float* __restrict__ gsum)
{
    __shared__ __align__(16) float As[16][68];   // [kk][m], +4 pad keeps 16B align, no conflicts
    __shared__ __align__(16) float Bs[16][128];  // [kk][f]
    __shared__ float gacc[128];

    const int tid = threadIdx.x;
    const int b = blockIdx.x >> 6;
    const int row = blockIdx.x & 63;
    const int tm = tid & 15;    // 16 threads along nodes (4 each)
    const int tn = tid >> 4;    // 16 threads along feats (8 each)
    const float* hb = hin + (size_t)b * K * 4096;
    if (MEAN && tid < 128) gacc[tid] = 0.f;

    float acc[4][8];
#pragma unroll
    for (int i = 0; i < 4; i++)
#pragma unroll
        for (int j = 0; j < 8; j++) acc[i][j] = 0.f;

    for (int k0 = 0; k0 < K; k0 += 16) {
        __syncthreads();
        // stage W rows k0..k0+15 (2048 floats) as float4
        {
            float4* Bs4 = (float4*)&Bs[0][0];
            const float4* W4 = (const float4*)(W + k0 * 128);
            Bs4[tid] = W4[tid];
            Bs4[tid + 256] = W4[tid + 256];
        }
        // stage aggregated A: 1024 elements, coalesced along m (=lane)
#pragma unroll
        for (int jj = 0; jj < 4; jj++) {
            const int e = tid + 256 * jj;
            const int kk = e >> 6;
            const int m = e & 63;
            const float* hk = hb + ((size_t)(k0 + kk) << 12) + row * 64;
            float s = 0.f;
            if (row > 0)  s += hk[m - 64];
            if (row < 63) s += hk[m + 64];
            if (m > 0)    s += hk[m - 1];
            if (m < 63)   s += hk[m + 1];
            const int deg = (row > 0) + (row < 63) + (m > 0) + (m < 63);
            As[kk][m] = s * (1.f / ((float)deg + 1e-6f));
        }
        __syncthreads();
#pragma unroll
        for (int kk = 0; kk < 16; kk++) {
            const float4 a4 = *(const float4*)&As[kk][tm * 4];
            const float4 b0 = *(const float4*)&Bs[kk][tn * 8];
            const float4 b1 = *(const float4*)&Bs[kk][tn * 8 + 4];
            const float av[4] = {a4.x, a4.y, a4.z, a4.w};
            const float bv[8] = {b0.x, b0.y, b0.z, b0.w, b1.x, b1.y, b1.z, b1.w};
#pragma unroll
            for (int i = 0; i < 4; i++)
#pragma unroll
                for (int j = 0; j < 8; j++)
                    acc[i][j] = fmaf(av[i], bv[j], acc[i][j]);
        }
    }

    // epilogue: + rowsum*bias, relu
    float bloc[8];
#pragma unroll
    for (int j = 0; j < 8; j++) bloc[j] = bias[tn * 8 + j];

    float vout[4][8];
#pragma unroll
    for (int i = 0; i < 4; i++) {
        const int m = tm * 4 + i;
        const int deg = (row > 0) + (row < 63) + (m > 0) + (m < 63);
        const float rs = (float)deg / ((float)deg + 1e-6f);
#pragma unroll
        for (int j = 0; j < 8; j++)
            vout[i][j] = fmaxf(fmaf(rs, bloc[j], acc[i][j]), 0.f);
    }

    if (!MEAN) {
#pragma unroll
        for (int j = 0; j < 8; j++) {
            float4 st = make_float4(vout[0][j], vout[1][j], vout[2][j], vout[3][j]);
            *(float4*)&hout[((size_t)b * 128 + tn * 8 + j) * 4096 + row * 64 + tm * 4] = st;
        }
    } else {
#pragma unroll
        for (int j = 0; j < 8; j++) {
            const float p = vout[0][j] + vout[1][j] + vout[2][j] + vout[3][j];
            atomicAdd(&gacc[tn * 8 + j], p);
        }
        __syncthreads();
        if (tid < 128) atomicAdd(&gsum[b * 128 + tid], gacc[tid] * (1.f / 4096.f));
    }
}

// ---------------- readout: per-batch block, 2-layer MLP ----------------
__global__ __launch_bounds__(256) void readout_kernel(
    const float* __restrict__ gsum, const float* __restrict__ r1w,
    const float* __restrict__ r1b, const float* __restrict__ r2w,
    const float* __restrict__ r2b, float* __restrict__ out)
{
    __shared__ float gs[128];
    __shared__ float g2[256];
    const int b = blockIdx.x;
    const int tid = threadIdx.x;
    if (tid < 128) gs[tid] = gsum[b * 128 + tid];
    __syncthreads();
    float a = r1b[tid];
#pragma unroll 8
    for (int k = 0; k < 128; k++) a = fmaf(gs[k], r1w[k * 256 + tid], a);
    g2[tid] = fmaxf(a, 0.f);
    __syncthreads();
    float a2 = r2b[tid];
#pragma unroll 8
    for (int k = 0; k < 256; k++) a2 = fmaf(g2[k], r2w[k * 256 + tid], a2);
    out[b * 256 + tid] = fmaxf(a2, 0.f);
}

extern "C" void kernel_launch(void* const* d_in, const int* in_sizes, int n_in,
                              void* d_out, int out_size, void* d_ws, size_t ws_size,
                              hipStream_t stream)
{
    const float* obs = (const float*)d_in[0];
    const float* e1w = (const float*)d_in[1];
    const float* e1b = (const float*)d_in[2];
    const float* e2w = (const float*)d_in[3];
    const float* e2b = (const float*)d_in[4];
    const float* g1w = (const float*)d_in[5];
    const float* g1b = (const float*)d_in[6];
    const float* g2w = (const float*)d_in[7];
    const float* g2b = (const float*)d_in[8];
    const float* g3w = (const float*)d_in[9];
    const float* g3b = (const float*)d_in[10];
    const float* r1w = (const float*)d_in[11];
    const float* r1b = (const float*)d_in[12];
    const float* r2w = (const float*)d_in[13];
    const float* r2b = (const float*)d_in[14];
    float* out = (float*)d_out;
    float* ws = (float*)d_ws;

    float* h0 = ws;                                 // 16*64*4096  = 4194304 floats (16 MB)
    float* h1 = ws + 4194304;                       // 16*128*4096 = 8388608 floats (32 MB)
    float* h2 = ws + 4194304 + 8388608;             // 32 MB
    float* gsum = ws + 4194304 + 2 * 8388608;       // 2048 floats

    hipLaunchKernelGGL(zero_kernel, dim3(8), dim3(256), 0, stream, gsum);
    hipLaunchKernelGGL(embed_kernel, dim3(256), dim3(256), 0, stream,
                       obs, e1w, e1b, e2w, e2b, h0);
    hipLaunchKernelGGL((gnn_kernel<64, false>), dim3(1024), dim3(256), 0, stream,
                       h0, g1w, g1b, h1, nullptr);
    hipLaunchKernelGGL((gnn_kernel<128, false>), dim3(1024), dim3(256), 0, stream,
                       h1, g2w, g2b, h2, nullptr);
    hipLaunchKernelGGL((gnn_kernel<128, true>), dim3(1024), dim3(256), 0, stream,
                       h2, g3w, g3b, nullptr, gsum);
    hipLaunchKernelGGL(readout_kernel, dim3(16), dim3(256), 0, stream,
                       gsum, r1w, r1b, r2w, r2b, out);
}